// Round 3
// baseline (919.106 us; speedup 1.0000x reference)
//
#include <hip/hip_runtime.h>

typedef unsigned short u16;
typedef __attribute__((ext_vector_type(8))) short bf16x8;
typedef __attribute__((ext_vector_type(8))) unsigned short u16x8;
typedef __attribute__((ext_vector_type(4))) unsigned short u16x4;
typedef __attribute__((ext_vector_type(4))) float f32x4;

__device__ inline float b2f(u16 u) {
    union { unsigned u32; float f; } x; x.u32 = ((unsigned)u) << 16; return x.f;
}
__device__ inline u16 f2b(float f) {
    union { float f; unsigned u; } x; x.f = f;
    unsigned r = x.u + 0x7fffu + ((x.u >> 16) & 1u);
    return (u16)(r >> 16);
}

#define GLOAD_LDS16(g, l) \
    __builtin_amdgcn_global_load_lds((const __attribute__((address_space(1))) void*)(const void*)(g), \
                                     (__attribute__((address_space(3))) void*)(void*)(l), 16, 0, 0)

// ---------------- LN1 + shift + window partition -> bf16 ----------------
__global__ __launch_bounds__(256)
void ln_win_kernel(const float* __restrict__ x, const float* __restrict__ g,
                   const float* __restrict__ b, u16* __restrict__ xw, int shift)
{
    int wid = blockIdx.x * 4 + (threadIdx.x >> 6);
    int lane = threadIdx.x & 63;
    int win = wid >> 6, tok = wid & 63;
    int bb = win >> 6, wib = win & 63;
    int h = (((wib >> 3) << 3) + (tok >> 3) + shift) & 63;
    int w = (((wib & 7) << 3) + (tok & 7) + shift) & 63;
    size_t src = ((size_t)bb * 4096 + h * 64 + w) * 256;
    float4 v = ((const float4*)(x + src))[lane];
    float s = v.x + v.y + v.z + v.w;
    float s2 = v.x*v.x + v.y*v.y + v.z*v.z + v.w*v.w;
    for (int k = 32; k > 0; k >>= 1) { s += __shfl_xor(s, k); s2 += __shfl_xor(s2, k); }
    float mean = s * (1.f/256.f);
    float var  = s2 * (1.f/256.f) - mean*mean;
    float rs = rsqrtf(var + 1e-5f);
    int c = lane * 4;
    u16x4 o;
    o[0] = f2b((v.x - mean) * rs * g[c+0] + b[c+0]);
    o[1] = f2b((v.y - mean) * rs * g[c+1] + b[c+1]);
    o[2] = f2b((v.z - mean) * rs * g[c+2] + b[c+2]);
    o[3] = f2b((v.w - mean) * rs * g[c+3] + b[c+3]);
    *(u16x4*)(xw + (size_t)wid * 256 + c) = o;
}

// ---------------- fused LN2(1e-5) then LN3(1e-6) -> bf16 -------------------
__global__ __launch_bounds__(256)
void ln2_kernel(const float* __restrict__ xin,
                const float* __restrict__ g1, const float* __restrict__ b1,
                const float* __restrict__ g2, const float* __restrict__ b2,
                u16* __restrict__ out)
{
    int wid = blockIdx.x * 4 + (threadIdx.x >> 6);
    int lane = threadIdx.x & 63;
    float4 v = ((const float4*)(xin + (size_t)wid * 256))[lane];
    float s = v.x + v.y + v.z + v.w;
    float s2 = v.x*v.x + v.y*v.y + v.z*v.z + v.w*v.w;
    for (int k = 32; k > 0; k >>= 1) { s += __shfl_xor(s, k); s2 += __shfl_xor(s2, k); }
    float mean = s * (1.f/256.f);
    float var  = s2 * (1.f/256.f) - mean*mean;
    float rs = rsqrtf(var + 1e-5f);
    int c = lane * 4;
    float y0 = (v.x - mean) * rs * g1[c+0] + b1[c+0];
    float y1 = (v.y - mean) * rs * g1[c+1] + b1[c+1];
    float y2 = (v.z - mean) * rs * g1[c+2] + b1[c+2];
    float y3 = (v.w - mean) * rs * g1[c+3] + b1[c+3];
    float t = y0 + y1 + y2 + y3;
    float t2 = y0*y0 + y1*y1 + y2*y2 + y3*y3;
    for (int k = 32; k > 0; k >>= 1) { t += __shfl_xor(t, k); t2 += __shfl_xor(t2, k); }
    float m2 = t * (1.f/256.f);
    float v2 = t2 * (1.f/256.f) - m2*m2;
    float rs2 = rsqrtf(v2 + 1e-6f);
    u16x4 o;
    o[0] = f2b((y0 - m2) * rs2 * g2[c+0] + b2[c+0]);
    o[1] = f2b((y1 - m2) * rs2 * g2[c+1] + b2[c+1]);
    o[2] = f2b((y2 - m2) * rs2 * g2[c+2] + b2[c+2]);
    o[3] = f2b((y3 - m2) * rs2 * g2[c+3] + b2[c+3]);
    *(u16x4*)(out + (size_t)wid * 256 + c) = o;
}

// ---------------- weight transpose f32[K][N] -> bf16 Wt[N][K] --------------
__global__ __launch_bounds__(256)
void transpose_w(const float* __restrict__ W, u16* __restrict__ Wt, int K, int N)
{
    __shared__ float t[32][33];
    int nb = blockIdx.x * 32, kb = blockIdx.y * 32;
    int tx = threadIdx.x & 31, ty = threadIdx.x >> 5;
    #pragma unroll
    for (int r = 0; r < 32; r += 8)
        t[ty + r][tx] = W[(size_t)(kb + ty + r) * N + nb + tx];
    __syncthreads();
    #pragma unroll
    for (int r = 0; r < 32; r += 8)
        Wt[(size_t)(nb + ty + r) * K + kb + tx] = f2b(t[tx][ty + r]);
}

// ---------------- bias(+mask) table: bmT[cls][h][k][q] * log2e -------------
__global__ __launch_bounds__(256)
void build_bias(const float* __restrict__ rpb, float* __restrict__ bmT)
{
    int idx = blockIdx.x * 256 + threadIdx.x;      // 4*8*64*64 = 131072
    int q = idx & 63, k = (idx >> 6) & 63, h = (idx >> 12) & 7, cls = idx >> 15;
    int qh = q >> 3, qw = q & 7, kh = k >> 3, kw = k & 7;
    float v = rpb[((qh - kh + 7) * 15 + (qw - kw + 7)) * 8 + h];
    int ch = cls >> 1, cw = cls & 1;
    int rq = (ch ? (qh < 4 ? 1 : 2) : 0) * 3 + (cw ? (qw < 4 ? 1 : 2) : 0);
    int rk = (ch ? (kh < 4 ? 1 : 2) : 0) * 3 + (cw ? (kw < 4 ? 1 : 2) : 0);
    if (rq != rk) v -= 100.f;
    bmT[idx] = v * 1.4426950408889634f;
}

// ---------------- 128x128 tile bf16 MFMA GEMM, templated epilogue ----------
// Operand-swapped: acc[j][i] = mfma(bf[j], af[i], .) so each lane owns 4
// consecutive OUTPUT COLS -> vectorized stores. XCD-chunked block swizzle.
// EPI 0: bf16 store (C = A*Bt^T + bias)
// EPI 2: f32 store with window-reverse row remap + residual add
template<int EPI>
__global__ __launch_bounds__(256)
void gemm_bf16(const u16* __restrict__ A, const u16* __restrict__ Bt,
               const float* __restrict__ bias, void* __restrict__ out,
               const float* __restrict__ resid, int M, int N, int K, int shift)
{
    __shared__ u16 As[128 * 32];
    __shared__ u16 Bs[128 * 32];
    const int tid = threadIdx.x;
    const int lane = tid & 63, wv = tid >> 6;
    // XCD-chunked bijective swizzle (T1)
    const int nwg = gridDim.x * gridDim.y;
    const int lid = blockIdx.y * gridDim.x + blockIdx.x;
    const int qq = nwg >> 3, r8 = nwg & 7;
    const int xcd = lid & 7, pos = lid >> 3;
    const int nid = (xcd < r8 ? xcd * (qq + 1) : r8 * (qq + 1) + (xcd - r8) * qq) + pos;
    const int bm = nid / gridDim.x, bn = nid % gridDim.x;
    const int wr = wv >> 1, wc = wv & 1;
    f32x4 acc[4][4] = {};   // [j=col frag][i=row frag]
    const int arow = wv * 16 + (lane >> 2);
    const int acol = (lane & 3) * 8;
    const u16* gA = A + (size_t)(bm * 128 + arow) * K + acol;
    const u16* gB = Bt + (size_t)(bn * 128 + arow) * K + acol;
    const int nk = K >> 5;
    const int g = lane >> 4, r = lane & 15;
    for (int kt = 0; kt < nk; ++kt) {
        __syncthreads();
        GLOAD_LDS16(gA,          As + wv * 512);
        GLOAD_LDS16(gA + 64 * K, As + 2048 + wv * 512);
        GLOAD_LDS16(gB,          Bs + wv * 512);
        GLOAD_LDS16(gB + 64 * K, Bs + 2048 + wv * 512);
        gA += 32; gB += 32;
        __syncthreads();
        bf16x8 af[4], bf[4];
        #pragma unroll
        for (int i = 0; i < 4; ++i)
            af[i] = *(const bf16x8*)(As + (wr * 64 + i * 16 + r) * 32 + g * 8);
        #pragma unroll
        for (int i = 0; i < 4; ++i)
            bf[i] = *(const bf16x8*)(Bs + (wc * 64 + i * 16 + r) * 32 + g * 8);
        #pragma unroll
        for (int j = 0; j < 4; ++j)
            #pragma unroll
            for (int i = 0; i < 4; ++i)
                acc[j][i] = __builtin_amdgcn_mfma_f32_16x16x32_bf16(bf[j], af[i], acc[j][i], 0, 0, 0);
    }
    // epilogue: row = ...+i*16+r  (lane&15), colbase = ...+j*16+g*4 (+rr)
    #pragma unroll
    for (int i = 0; i < 4; ++i) {
        const int row = bm * 128 + wr * 64 + i * 16 + r;
        size_t orow;
        if (EPI == 2) {
            int win = row >> 6, tok = row & 63;
            int bb = win >> 6, wib = win & 63;
            int h = (((wib >> 3) << 3) + (tok >> 3) + shift) & 63;
            int w = (((wib & 7) << 3) + (tok & 7) + shift) & 63;
            orow = (size_t)bb * 4096 + h * 64 + w;
        } else {
            orow = (size_t)row;
        }
        #pragma unroll
        for (int j = 0; j < 4; ++j) {
            const int colb = bn * 128 + wc * 64 + j * 16 + g * 4;
            const float4 bv = *(const float4*)(bias + colb);
            if (EPI == 0) {
                u16x4 o;
                o[0] = f2b(acc[j][i][0] + bv.x);
                o[1] = f2b(acc[j][i][1] + bv.y);
                o[2] = f2b(acc[j][i][2] + bv.z);
                o[3] = f2b(acc[j][i][3] + bv.w);
                *(u16x4*)((u16*)out + (size_t)row * N + colb) = o;
            } else {
                const float4 rv = *(const float4*)(resid + orow * N + colb);
                float4 o;
                o.x = rv.x + acc[j][i][0] + bv.x;
                o.y = rv.y + acc[j][i][1] + bv.y;
                o.z = rv.z + acc[j][i][2] + bv.z;
                o.w = rv.w + acc[j][i][3] + bv.w;
                *(float4*)((float*)out + orow * N + colb) = o;
            }
        }
    }
}

// ---------------- fused MLP: out = x1 + gelu(ln2x @ W1 + b1) @ W2 + b2 -----
// Block = 64 token rows, 4 waves. Hidden processed in 4 quarters of 256;
// each wave owns a 64-col slice in both phases. H quarter lives in LDS.
__global__ __launch_bounds__(256, 2)
void fused_mlp(const u16* __restrict__ A, const u16* __restrict__ W1t,
               const float* __restrict__ b1, const u16* __restrict__ W2t,
               const float* __restrict__ b2, const float* __restrict__ x1,
               float* __restrict__ out)
{
    __shared__ u16 Hs[64][264];   // 33 KB; row stride 528 B: 16B-aligned, 2-way banks
    const int tid = threadIdx.x, lane = tid & 63, wv = tid >> 6;
    const int g = lane >> 4, r = lane & 15;
    const size_t row0 = (size_t)blockIdx.x * 64;
    f32x4 p2[4][4] = {};          // [j=out-col frag][i=row frag]
    for (int q = 0; q < 4; ++q) {
        // ---- phase 1: H[:, q*256 + wv*64 .. +64] = A @ W1 slice
        f32x4 p1[4][4] = {};
        const u16* w1p = W1t + ((size_t)q * 256 + wv * 64) * 256;
        #pragma unroll
        for (int ks = 0; ks < 8; ++ks) {
            bf16x8 af[4], wb[4];
            #pragma unroll
            for (int i = 0; i < 4; ++i)
                af[i] = *(const bf16x8*)(A + (row0 + i * 16 + r) * 256 + ks * 32 + g * 8);
            #pragma unroll
            for (int j = 0; j < 4; ++j)
                wb[j] = *(const bf16x8*)(w1p + (size_t)(j * 16 + r) * 256 + ks * 32 + g * 8);
            #pragma unroll
            for (int j = 0; j < 4; ++j)
                #pragma unroll
                for (int i = 0; i < 4; ++i)
                    p1[j][i] = __builtin_amdgcn_mfma_f32_16x16x32_bf16(wb[j], af[i], p1[j][i], 0, 0, 0);
        }
        __syncthreads();   // previous quarter's phase-2 reads done
        // ---- gelu + pack to LDS
        #pragma unroll
        for (int j = 0; j < 4; ++j) {
            const int cq = wv * 64 + j * 16 + g * 4;          // col within quarter
            const float4 bv = *(const float4*)(b1 + q * 256 + cq);
            #pragma unroll
            for (int i = 0; i < 4; ++i) {
                u16x4 hw;
                #pragma unroll
                for (int rr = 0; rr < 4; ++rr) {
                    float v = p1[j][i][rr] + ((const float*)&bv)[rr];
                    hw[rr] = f2b(0.5f * v * (1.f + erff(v * 0.70710678118654752f)));
                }
                *(u16x4*)(&Hs[i * 16 + r][cq]) = hw;
            }
        }
        __syncthreads();
        // ---- phase 2: p2 += H_q @ W2 slice (wave's 64 out cols)
        const u16* w2p = W2t + (size_t)(wv * 64) * 1024 + q * 256;
        #pragma unroll
        for (int ks = 0; ks < 8; ++ks) {
            bf16x8 hf[4], w2[4];
            #pragma unroll
            for (int i = 0; i < 4; ++i)
                hf[i] = *(const bf16x8*)(&Hs[i * 16 + r][ks * 32 + g * 8]);
            #pragma unroll
            for (int j = 0; j < 4; ++j)
                w2[j] = *(const bf16x8*)(w2p + (size_t)(j * 16 + r) * 1024 + ks * 32 + g * 8);
            #pragma unroll
            for (int j = 0; j < 4; ++j)
                #pragma unroll
                for (int i = 0; i < 4; ++i)
                    p2[j][i] = __builtin_amdgcn_mfma_f32_16x16x32_bf16(w2[j], hf[i], p2[j][i], 0, 0, 0);
        }
    }
    // ---- epilogue: residual + bias, f32 out
    #pragma unroll
    for (int j = 0; j < 4; ++j) {
        const int col = wv * 64 + j * 16 + g * 4;
        const float4 bv = *(const float4*)(b2 + col);
        #pragma unroll
        for (int i = 0; i < 4; ++i) {
            const size_t row = row0 + i * 16 + r;
            const float4 rv = *(const float4*)(x1 + row * 256 + col);
            float4 o;
            o.x = rv.x + p2[j][i][0] + bv.x;
            o.y = rv.y + p2[j][i][1] + bv.y;
            o.z = rv.z + p2[j][i][2] + bv.z;
            o.w = rv.w + p2[j][i][3] + bv.w;
            *(float4*)(out + row * 256 + col) = o;
        }
    }
}

// ---------------- MFMA attention: one block per window, wave = 2 heads -----
template<int SHIFTED>
__global__ __launch_bounds__(256)
void attn_mfma(const u16* __restrict__ qkv, const float* __restrict__ bmT,
               u16* __restrict__ out)
{
    __shared__ u16 pbuf[4][64 * 72];
    __shared__ u16 vbuf[4][32 * 72];
    const int tid = threadIdx.x, lane = tid & 63, wv = tid >> 6;
    const int g = lane >> 4, r = lane & 15;
    const int win = blockIdx.x;
    u16* P  = pbuf[wv];
    u16* Vt = vbuf[wv];
    const u16* base = qkv + (size_t)win * 64 * 768;
    int cls = 0;
    if (SHIFTED) {
        int wib = win & 63;
        cls = (((wib >> 3) == 7) ? 2 : 0) + (((wib & 7) == 7) ? 1 : 0);
    }
    const float sc = 0.17677669529663687f * 1.4426950408889634f;

    for (int hh = 0; hh < 2; ++hh) {
        const int h = wv * 2 + hh;
        const float* bmh = bmT + ((size_t)cls * 8 + h) * 4096;
        bf16x8 kf[4], qf[4];
        #pragma unroll
        for (int i = 0; i < 4; ++i) {
            kf[i] = *(const bf16x8*)(base + (size_t)(i * 16 + r) * 768 + 256 + h * 32 + g * 8);
            qf[i] = *(const bf16x8*)(base + (size_t)(i * 16 + r) * 768 +       h * 32 + g * 8);
        }
        #pragma unroll
        for (int d0 = 0; d0 < 32; d0 += 8) {
            u16x8 vv = *(const u16x8*)(base + (size_t)lane * 768 + 512 + h * 32 + d0);
            #pragma unroll
            for (int e = 0; e < 8; ++e) Vt[(d0 + e) * 72 + lane] = vv[e];
        }
        f32x4 acc[4][4] = {};
        #pragma unroll
        for (int i = 0; i < 4; ++i)
            #pragma unroll
            for (int j = 0; j < 4; ++j)
                acc[i][j] = __builtin_amdgcn_mfma_f32_16x16x32_bf16(kf[i], qf[j], acc[i][j], 0, 0, 0);
        #pragma unroll
        for (int i = 0; i < 4; ++i) {
            const int kb = (i * 16 + g * 4) * 64;
            #pragma unroll
            for (int j = 0; j < 4; ++j) {
                const int qq = j * 16 + r;
                #pragma unroll
                for (int rr = 0; rr < 4; ++rr)
                    acc[i][j][rr] = acc[i][j][rr] * sc + bmh[kb + rr * 64 + qq];
            }
        }
        float inv_[4];
        #pragma unroll
        for (int j = 0; j < 4; ++j) {
            float m = acc[0][j][0];
            #pragma unroll
            for (int i = 0; i < 4; ++i)
                #pragma unroll
                for (int rr = 0; rr < 4; ++rr) m = fmaxf(m, acc[i][j][rr]);
            m = fmaxf(m, __shfl_xor(m, 16));
            m = fmaxf(m, __shfl_xor(m, 32));
            float s = 0.f;
            #pragma unroll
            for (int i = 0; i < 4; ++i)
                #pragma unroll
                for (int rr = 0; rr < 4; ++rr) {
                    float p = exp2f(acc[i][j][rr] - m);
                    acc[i][j][rr] = p; s += p;
                }
            s += __shfl_xor(s, 16);
            s += __shfl_xor(s, 32);
            inv_[j] = 1.f / s;
        }
        #pragma unroll
        for (int j = 0; j < 4; ++j) {
            const float iv = inv_[j];
            #pragma unroll
            for (int i = 0; i < 4; ++i) {
                u16x4 w;
                #pragma unroll
                for (int rr = 0; rr < 4; ++rr) w[rr] = f2b(acc[i][j][rr] * iv);
                *(u16x4*)(P + (j * 16 + r) * 72 + i * 16 + g * 4) = w;
            }
        }
        // PV, operand-swapped: lane owns 4 consecutive d cols
        f32x4 o[2][4] = {};
        #pragma unroll
        for (int ks = 0; ks < 2; ++ks) {
            bf16x8 pa[4], vb[2];
            #pragma unroll
            for (int i = 0; i < 4; ++i)
                pa[i] = *(const bf16x8*)(P + (i * 16 + r) * 72 + ks * 32 + g * 8);
            #pragma unroll
            for (int j = 0; j < 2; ++j)
                vb[j] = *(const bf16x8*)(Vt + (j * 16 + r) * 72 + ks * 32 + g * 8);
            #pragma unroll
            for (int j = 0; j < 2; ++j)
                #pragma unroll
                for (int i = 0; i < 4; ++i)
                    o[j][i] = __builtin_amdgcn_mfma_f32_16x16x32_bf16(vb[j], pa[i], o[j][i], 0, 0, 0);
        }
        u16* op = out + (size_t)win * 64 * 256 + h * 32;
        #pragma unroll
        for (int i = 0; i < 4; ++i) {
            const int qrow = i * 16 + r;
            #pragma unroll
            for (int j = 0; j < 2; ++j) {
                u16x4 w;
                #pragma unroll
                for (int rr = 0; rr < 4; ++rr) w[rr] = f2b(o[j][i][rr]);
                *(u16x4*)(op + (size_t)qrow * 256 + j * 16 + g * 4) = w;
            }
        }
    }
}

// ---------------------------------------------------------------------------
extern "C" void kernel_launch(void* const* d_in, const int* in_sizes, int n_in,
                              void* d_out, int out_size, void* d_ws, size_t ws_size,
                              hipStream_t stream)
{
    (void)in_sizes; (void)n_in; (void)out_size; (void)ws_size;
    const float* x = (const float*)d_in[0];
    char* ws = (char*)d_ws;
    size_t off = 0;
    auto alloc = [&](size_t bytes) { void* p = ws + off; off += (bytes + 255) & ~(size_t)255; return p; };

    u16 *wtq[2], *wto[2], *wt1[2], *wt2[2];
    float* bmT[2];
    for (int i = 0; i < 2; ++i) {
        wtq[i] = (u16*)alloc((size_t)768 * 256 * 2);
        wto[i] = (u16*)alloc((size_t)256 * 256 * 2);
        wt1[i] = (u16*)alloc((size_t)1024 * 256 * 2);
        wt2[i] = (u16*)alloc((size_t)256 * 1024 * 2);
        bmT[i] = (float*)alloc((size_t)4 * 8 * 64 * 64 * 4);
    }
    u16*  xw  = (u16*)alloc((size_t)65536 * 256 * 2);
    u16*  big = (u16*)alloc((size_t)65536 * 768 * 2);
    float* x1 = (float*)alloc((size_t)65536 * 256 * 4);
    float* outp = (float*)d_out;

    for (int blk = 0; blk < 2; ++blk) {
        const float* const* P = (const float* const*)(d_in + 1 + blk * 15);
        transpose_w<<<dim3(768 / 32, 256 / 32), 256, 0, stream>>>(P[2], wtq[blk], 256, 768);
        transpose_w<<<dim3(256 / 32, 256 / 32), 256, 0, stream>>>(P[5], wto[blk], 256, 256);
        transpose_w<<<dim3(1024 / 32, 256 / 32), 256, 0, stream>>>(P[11], wt1[blk], 256, 1024);
        transpose_w<<<dim3(256 / 32, 1024 / 32), 256, 0, stream>>>(P[13], wt2[blk], 1024, 256);
        build_bias<<<512, 256, 0, stream>>>(P[4], bmT[blk]);
    }

    for (int blk = 0; blk < 2; ++blk) {
        const float* const* P = (const float* const*)(d_in + 1 + blk * 15);
        const int sh = blk ? 4 : 0;
        const float* xin = blk ? outp : x;

        ln_win_kernel<<<16384, 256, 0, stream>>>(xin, P[0], P[1], xw, sh);
        gemm_bf16<0><<<dim3(6, 512), 256, 0, stream>>>(xw, wtq[blk], P[3], big, nullptr, 65536, 768, 256, 0);
        if (blk) attn_mfma<1><<<1024, 256, 0, stream>>>(big, bmT[blk], xw);
        else     attn_mfma<0><<<1024, 256, 0, stream>>>(big, bmT[blk], xw);
        gemm_bf16<2><<<dim3(2, 512), 256, 0, stream>>>(xw, wto[blk], P[6], x1, xin, 65536, 256, 256, sh);
        ln2_kernel<<<16384, 256, 0, stream>>>(x1, P[7], P[8], P[9], P[10], xw);
        fused_mlp<<<1024, 256, 0, stream>>>(xw, wt1[blk], P[12], wt2[blk], P[14], x1, outp);
    }
}

// Round 4
// 802.319 us; speedup vs baseline: 1.1456x; 1.1456x over previous
//
#include <hip/hip_runtime.h>

typedef unsigned short u16;
typedef __attribute__((ext_vector_type(8))) short bf16x8;
typedef __attribute__((ext_vector_type(8))) unsigned short u16x8;
typedef __attribute__((ext_vector_type(4))) unsigned short u16x4;
typedef __attribute__((ext_vector_type(4))) float f32x4;

__device__ inline float b2f(u16 u) {
    union { unsigned u32; float f; } x; x.u32 = ((unsigned)u) << 16; return x.f;
}
__device__ inline u16 f2b(float f) {
    union { float f; unsigned u; } x; x.f = f;
    unsigned r = x.u + 0x7fffu + ((x.u >> 16) & 1u);
    return (u16)(r >> 16);
}

// fast exact-erf GELU (A&S 7.1.26, |err|<1.5e-7)
__device__ inline float fast_gelu(float v) {
    float x = fabsf(v) * 0.70710678118654752f;
    float t = __builtin_amdgcn_rcpf(1.0f + 0.3275911f * x);
    float e = __expf(-x * x);
    float poly = ((((1.061405429f * t - 1.453152027f) * t + 1.421413741f) * t
                   - 0.284496736f) * t + 0.254829592f) * t;
    float erfv = 1.0f - poly * e;
    float w = copysignf(erfv, v);
    return 0.5f * v * (1.0f + w);
}

#define GLOAD_LDS16(g, l) \
    __builtin_amdgcn_global_load_lds((const __attribute__((address_space(1))) void*)(const void*)(g), \
                                     (__attribute__((address_space(3))) void*)(void*)(l), 16, 0, 0)

// ---------------- LN1 + shift + window partition -> bf16 ----------------
__global__ __launch_bounds__(256)
void ln_win_kernel(const float* __restrict__ x, const float* __restrict__ g,
                   const float* __restrict__ b, u16* __restrict__ xw, int shift)
{
    int wid = blockIdx.x * 4 + (threadIdx.x >> 6);
    int lane = threadIdx.x & 63;
    int win = wid >> 6, tok = wid & 63;
    int bb = win >> 6, wib = win & 63;
    int h = (((wib >> 3) << 3) + (tok >> 3) + shift) & 63;
    int w = (((wib & 7) << 3) + (tok & 7) + shift) & 63;
    size_t src = ((size_t)bb * 4096 + h * 64 + w) * 256;
    float4 v = ((const float4*)(x + src))[lane];
    float s = v.x + v.y + v.z + v.w;
    float s2 = v.x*v.x + v.y*v.y + v.z*v.z + v.w*v.w;
    for (int k = 32; k > 0; k >>= 1) { s += __shfl_xor(s, k); s2 += __shfl_xor(s2, k); }
    float mean = s * (1.f/256.f);
    float var  = s2 * (1.f/256.f) - mean*mean;
    float rs = rsqrtf(var + 1e-5f);
    int c = lane * 4;
    u16x4 o;
    o[0] = f2b((v.x - mean) * rs * g[c+0] + b[c+0]);
    o[1] = f2b((v.y - mean) * rs * g[c+1] + b[c+1]);
    o[2] = f2b((v.z - mean) * rs * g[c+2] + b[c+2]);
    o[3] = f2b((v.w - mean) * rs * g[c+3] + b[c+3]);
    *(u16x4*)(xw + (size_t)wid * 256 + c) = o;
}

// ---------------- fused LN2(1e-5) then LN3(1e-6) -> bf16 -------------------
__global__ __launch_bounds__(256)
void ln2_kernel(const float* __restrict__ xin,
                const float* __restrict__ g1, const float* __restrict__ b1,
                const float* __restrict__ g2, const float* __restrict__ b2,
                u16* __restrict__ out)
{
    int wid = blockIdx.x * 4 + (threadIdx.x >> 6);
    int lane = threadIdx.x & 63;
    float4 v = ((const float4*)(xin + (size_t)wid * 256))[lane];
    float s = v.x + v.y + v.z + v.w;
    float s2 = v.x*v.x + v.y*v.y + v.z*v.z + v.w*v.w;
    for (int k = 32; k > 0; k >>= 1) { s += __shfl_xor(s, k); s2 += __shfl_xor(s2, k); }
    float mean = s * (1.f/256.f);
    float var  = s2 * (1.f/256.f) - mean*mean;
    float rs = rsqrtf(var + 1e-5f);
    int c = lane * 4;
    float y0 = (v.x - mean) * rs * g1[c+0] + b1[c+0];
    float y1 = (v.y - mean) * rs * g1[c+1] + b1[c+1];
    float y2 = (v.z - mean) * rs * g1[c+2] + b1[c+2];
    float y3 = (v.w - mean) * rs * g1[c+3] + b1[c+3];
    float t = y0 + y1 + y2 + y3;
    float t2 = y0*y0 + y1*y1 + y2*y2 + y3*y3;
    for (int k = 32; k > 0; k >>= 1) { t += __shfl_xor(t, k); t2 += __shfl_xor(t2, k); }
    float m2 = t * (1.f/256.f);
    float v2 = t2 * (1.f/256.f) - m2*m2;
    float rs2 = rsqrtf(v2 + 1e-6f);
    u16x4 o;
    o[0] = f2b((y0 - m2) * rs2 * g2[c+0] + b2[c+0]);
    o[1] = f2b((y1 - m2) * rs2 * g2[c+1] + b2[c+1]);
    o[2] = f2b((y2 - m2) * rs2 * g2[c+2] + b2[c+2]);
    o[3] = f2b((y3 - m2) * rs2 * g2[c+3] + b2[c+3]);
    *(u16x4*)(out + (size_t)wid * 256 + c) = o;
}

// ---------------- weight transpose f32[K][N] -> bf16 Wt[N][K] --------------
__global__ __launch_bounds__(256)
void transpose_w(const float* __restrict__ W, u16* __restrict__ Wt, int K, int N)
{
    __shared__ float t[32][33];
    int nb = blockIdx.x * 32, kb = blockIdx.y * 32;
    int tx = threadIdx.x & 31, ty = threadIdx.x >> 5;
    #pragma unroll
    for (int r = 0; r < 32; r += 8)
        t[ty + r][tx] = W[(size_t)(kb + ty + r) * N + nb + tx];
    __syncthreads();
    #pragma unroll
    for (int r = 0; r < 32; r += 8)
        Wt[(size_t)(nb + ty + r) * K + kb + tx] = f2b(t[tx][ty + r]);
}

// ---------------- bias(+mask) table: bmT[cls][h][k][q] * log2e -------------
__global__ __launch_bounds__(256)
void build_bias(const float* __restrict__ rpb, float* __restrict__ bmT)
{
    int idx = blockIdx.x * 256 + threadIdx.x;      // 4*8*64*64 = 131072
    int q = idx & 63, k = (idx >> 6) & 63, h = (idx >> 12) & 7, cls = idx >> 15;
    int qh = q >> 3, qw = q & 7, kh = k >> 3, kw = k & 7;
    float v = rpb[((qh - kh + 7) * 15 + (qw - kw + 7)) * 8 + h];
    int ch = cls >> 1, cw = cls & 1;
    int rq = (ch ? (qh < 4 ? 1 : 2) : 0) * 3 + (cw ? (qw < 4 ? 1 : 2) : 0);
    int rk = (ch ? (kh < 4 ? 1 : 2) : 0) * 3 + (cw ? (kw < 4 ? 1 : 2) : 0);
    if (rq != rk) v -= 100.f;
    bmT[idx] = v * 1.4426950408889634f;
}

// ---------------- 128x128 tile bf16 MFMA GEMM, double-buffered (T3-min) ----
// Operand-swapped epilogue (lane owns 4 consecutive cols), XCD swizzle (T1).
// EPI 0: bf16 store (C = A*Bt^T + bias)
// EPI 2: f32 store with window-reverse row remap + residual add
template<int EPI>
__global__ __launch_bounds__(256)
void gemm_bf16(const u16* __restrict__ A, const u16* __restrict__ Bt,
               const float* __restrict__ bias, void* __restrict__ out,
               const float* __restrict__ resid, int M, int N, int K, int shift)
{
    __shared__ u16 As[2][128 * 32];
    __shared__ u16 Bs[2][128 * 32];
    const int tid = threadIdx.x;
    const int lane = tid & 63, wv = tid >> 6;
    // XCD-chunked bijective swizzle (T1)
    const int nwg = gridDim.x * gridDim.y;
    const int lid = blockIdx.y * gridDim.x + blockIdx.x;
    const int qq = nwg >> 3, r8 = nwg & 7;
    const int xcd = lid & 7, pos = lid >> 3;
    const int nid = (xcd < r8 ? xcd * (qq + 1) : r8 * (qq + 1) + (xcd - r8) * qq) + pos;
    const int bm = nid / gridDim.x, bn = nid % gridDim.x;
    const int wr = wv >> 1, wc = wv & 1;
    f32x4 acc[4][4] = {};   // [j=col frag][i=row frag]
    const int arow = wv * 16 + (lane >> 2);
    const int acol = (lane & 3) * 8;
    const u16* gA = A + (size_t)(bm * 128 + arow) * K + acol;
    const u16* gB = Bt + (size_t)(bn * 128 + arow) * K + acol;
    const int nk = K >> 5;
    const int g = lane >> 4, r = lane & 15;
    // prologue: stage kt=0 into buf 0
    GLOAD_LDS16(gA,          As[0] + wv * 512);
    GLOAD_LDS16(gA + 64 * K, As[0] + 2048 + wv * 512);
    GLOAD_LDS16(gB,          Bs[0] + wv * 512);
    GLOAD_LDS16(gB + 64 * K, Bs[0] + 2048 + wv * 512);
    gA += 32; gB += 32;
    __syncthreads();
    int cur = 0;
    for (int kt = 0; kt < nk; ++kt) {
        if (kt + 1 < nk) {           // prefetch next tile into other buffer
            GLOAD_LDS16(gA,          As[cur ^ 1] + wv * 512);
            GLOAD_LDS16(gA + 64 * K, As[cur ^ 1] + 2048 + wv * 512);
            GLOAD_LDS16(gB,          Bs[cur ^ 1] + wv * 512);
            GLOAD_LDS16(gB + 64 * K, Bs[cur ^ 1] + 2048 + wv * 512);
            gA += 32; gB += 32;
        }
        bf16x8 af[4], bf[4];
        #pragma unroll
        for (int i = 0; i < 4; ++i)
            af[i] = *(const bf16x8*)(As[cur] + (wr * 64 + i * 16 + r) * 32 + g * 8);
        #pragma unroll
        for (int i = 0; i < 4; ++i)
            bf[i] = *(const bf16x8*)(Bs[cur] + (wc * 64 + i * 16 + r) * 32 + g * 8);
        #pragma unroll
        for (int j = 0; j < 4; ++j)
            #pragma unroll
            for (int i = 0; i < 4; ++i)
                acc[j][i] = __builtin_amdgcn_mfma_f32_16x16x32_bf16(bf[j], af[i], acc[j][i], 0, 0, 0);
        __syncthreads();             // drains vmcnt: prefetched loads had MFMA time to land
        cur ^= 1;
    }
    // epilogue: row = ...+i*16+r, colbase = ...+j*16+g*4
    #pragma unroll
    for (int i = 0; i < 4; ++i) {
        const int row = bm * 128 + wr * 64 + i * 16 + r;
        size_t orow;
        if (EPI == 2) {
            int win = row >> 6, tok = row & 63;
            int bb = win >> 6, wib = win & 63;
            int h = (((wib >> 3) << 3) + (tok >> 3) + shift) & 63;
            int w = (((wib & 7) << 3) + (tok & 7) + shift) & 63;
            orow = (size_t)bb * 4096 + h * 64 + w;
        } else {
            orow = (size_t)row;
        }
        #pragma unroll
        for (int j = 0; j < 4; ++j) {
            const int colb = bn * 128 + wc * 64 + j * 16 + g * 4;
            const float4 bv = *(const float4*)(bias + colb);
            if (EPI == 0) {
                u16x4 o;
                o[0] = f2b(acc[j][i][0] + bv.x);
                o[1] = f2b(acc[j][i][1] + bv.y);
                o[2] = f2b(acc[j][i][2] + bv.z);
                o[3] = f2b(acc[j][i][3] + bv.w);
                *(u16x4*)((u16*)out + (size_t)row * N + colb) = o;
            } else {
                const float4 rv = *(const float4*)(resid + orow * N + colb);
                float4 o;
                o.x = rv.x + acc[j][i][0] + bv.x;
                o.y = rv.y + acc[j][i][1] + bv.y;
                o.z = rv.z + acc[j][i][2] + bv.z;
                o.w = rv.w + acc[j][i][3] + bv.w;
                *(float4*)((float*)out + orow * N + colb) = o;
            }
        }
    }
}

// ---------------- fused MLP v2: out = x1 + gelu(A @ W1 + b1) @ W2 + b2 -----
// 512 thr / 8 waves, 64 rows per block. Hidden in 4 slices of 256.
// Per slice: wave computes 64x32 H slice (p1 = 32 VGPR), gelu -> LDS,
// then p2(64x32 out cols) += H_slice @ W2 slice. p2 = 32 VGPR persistent.
__global__ __launch_bounds__(512, 2)
void fused_mlp(const u16* __restrict__ A, const u16* __restrict__ W1t,
               const float* __restrict__ b1, const u16* __restrict__ W2t,
               const float* __restrict__ b2, const float* __restrict__ x1,
               float* __restrict__ out)
{
    __shared__ u16 Hs[64][264];   // 33.8 KB; 16B-aligned rows, balanced banks
    const int tid = threadIdx.x, lane = tid & 63, wv = tid >> 6;
    const int g = lane >> 4, r = lane & 15;
    const size_t row0 = (size_t)blockIdx.x * 64;
    const int oc = wv * 32;                 // wave's 32 output cols
    f32x4 p2[2][4] = {};                    // [j][i]
    for (int s = 0; s < 4; ++s) {
        const int hc = s * 256 + wv * 32;   // wave's 32 hidden cols this slice
        f32x4 p1[2][4] = {};
        const u16* w1p = W1t + (size_t)hc * 256;
        #pragma unroll
        for (int ks = 0; ks < 8; ++ks) {
            bf16x8 af[4], wb[2];
            #pragma unroll
            for (int i = 0; i < 4; ++i)
                af[i] = *(const bf16x8*)(A + (row0 + i * 16 + r) * 256 + ks * 32 + g * 8);
            #pragma unroll
            for (int j = 0; j < 2; ++j)
                wb[j] = *(const bf16x8*)(w1p + (size_t)(j * 16 + r) * 256 + ks * 32 + g * 8);
            #pragma unroll
            for (int j = 0; j < 2; ++j)
                #pragma unroll
                for (int i = 0; i < 4; ++i)
                    p1[j][i] = __builtin_amdgcn_mfma_f32_16x16x32_bf16(wb[j], af[i], p1[j][i], 0, 0, 0);
        }
        __syncthreads();   // previous slice's phase-2 readers done
        #pragma unroll
        for (int j = 0; j < 2; ++j) {
            const float4 bv = *(const float4*)(b1 + hc + j * 16 + g * 4);
            #pragma unroll
            for (int i = 0; i < 4; ++i) {
                u16x4 hw;
                #pragma unroll
                for (int rr = 0; rr < 4; ++rr) {
                    float v = p1[j][i][rr] + ((const float*)&bv)[rr];
                    hw[rr] = f2b(fast_gelu(v));
                }
                *(u16x4*)(&Hs[i * 16 + r][wv * 32 + j * 16 + g * 4]) = hw;
            }
        }
        __syncthreads();
        const u16* w2p = W2t + (size_t)oc * 1024 + s * 256;
        #pragma unroll
        for (int ks = 0; ks < 8; ++ks) {
            bf16x8 hf[4], w2f[2];
            #pragma unroll
            for (int i = 0; i < 4; ++i)
                hf[i] = *(const bf16x8*)(&Hs[i * 16 + r][ks * 32 + g * 8]);
            #pragma unroll
            for (int j = 0; j < 2; ++j)
                w2f[j] = *(const bf16x8*)(w2p + (size_t)(j * 16 + r) * 1024 + ks * 32 + g * 8);
            #pragma unroll
            for (int j = 0; j < 2; ++j)
                #pragma unroll
                for (int i = 0; i < 4; ++i)
                    p2[j][i] = __builtin_amdgcn_mfma_f32_16x16x32_bf16(w2f[j], hf[i], p2[j][i], 0, 0, 0);
        }
    }
    // epilogue: residual + bias, f32
    #pragma unroll
    for (int j = 0; j < 2; ++j) {
        const int col = oc + j * 16 + g * 4;
        const float4 bv = *(const float4*)(b2 + col);
        #pragma unroll
        for (int i = 0; i < 4; ++i) {
            const size_t row = row0 + i * 16 + r;
            const float4 rv = *(const float4*)(x1 + row * 256 + col);
            float4 o;
            o.x = rv.x + p2[j][i][0] + bv.x;
            o.y = rv.y + p2[j][i][1] + bv.y;
            o.z = rv.z + p2[j][i][2] + bv.z;
            o.w = rv.w + p2[j][i][3] + bv.w;
            *(float4*)(out + row * 256 + col) = o;
        }
    }
}

// ---------------- MFMA attention: one block per window, wave = 2 heads -----
template<int SHIFTED>
__global__ __launch_bounds__(256)
void attn_mfma(const u16* __restrict__ qkv, const float* __restrict__ bmT,
               u16* __restrict__ out)
{
    __shared__ u16 pbuf[4][64 * 72];
    __shared__ u16 vbuf[4][32 * 72];
    const int tid = threadIdx.x, lane = tid & 63, wv = tid >> 6;
    const int g = lane >> 4, r = lane & 15;
    const int win = blockIdx.x;
    u16* P  = pbuf[wv];
    u16* Vt = vbuf[wv];
    const u16* base = qkv + (size_t)win * 64 * 768;
    int cls = 0;
    if (SHIFTED) {
        int wib = win & 63;
        cls = (((wib >> 3) == 7) ? 2 : 0) + (((wib & 7) == 7) ? 1 : 0);
    }
    const float sc = 0.17677669529663687f * 1.4426950408889634f;

    for (int hh = 0; hh < 2; ++hh) {
        const int h = wv * 2 + hh;
        const float* bmh = bmT + ((size_t)cls * 8 + h) * 4096;
        bf16x8 kf[4], qf[4];
        #pragma unroll
        for (int i = 0; i < 4; ++i) {
            kf[i] = *(const bf16x8*)(base + (size_t)(i * 16 + r) * 768 + 256 + h * 32 + g * 8);
            qf[i] = *(const bf16x8*)(base + (size_t)(i * 16 + r) * 768 +       h * 32 + g * 8);
        }
        #pragma unroll
        for (int d0 = 0; d0 < 32; d0 += 8) {
            u16x8 vv = *(const u16x8*)(base + (size_t)lane * 768 + 512 + h * 32 + d0);
            #pragma unroll
            for (int e = 0; e < 8; ++e) Vt[(d0 + e) * 72 + lane] = vv[e];
        }
        f32x4 acc[4][4] = {};
        #pragma unroll
        for (int i = 0; i < 4; ++i)
            #pragma unroll
            for (int j = 0; j < 4; ++j)
                acc[i][j] = __builtin_amdgcn_mfma_f32_16x16x32_bf16(kf[i], qf[j], acc[i][j], 0, 0, 0);
        #pragma unroll
        for (int i = 0; i < 4; ++i) {
            const int kb = (i * 16 + g * 4) * 64;
            #pragma unroll
            for (int j = 0; j < 4; ++j) {
                const int qq = j * 16 + r;
                #pragma unroll
                for (int rr = 0; rr < 4; ++rr)
                    acc[i][j][rr] = acc[i][j][rr] * sc + bmh[kb + rr * 64 + qq];
            }
        }
        float inv_[4];
        #pragma unroll
        for (int j = 0; j < 4; ++j) {
            float m = acc[0][j][0];
            #pragma unroll
            for (int i = 0; i < 4; ++i)
                #pragma unroll
                for (int rr = 0; rr < 4; ++rr) m = fmaxf(m, acc[i][j][rr]);
            m = fmaxf(m, __shfl_xor(m, 16));
            m = fmaxf(m, __shfl_xor(m, 32));
            float s = 0.f;
            #pragma unroll
            for (int i = 0; i < 4; ++i)
                #pragma unroll
                for (int rr = 0; rr < 4; ++rr) {
                    float p = exp2f(acc[i][j][rr] - m);
                    acc[i][j][rr] = p; s += p;
                }
            s += __shfl_xor(s, 16);
            s += __shfl_xor(s, 32);
            inv_[j] = 1.f / s;
        }
        #pragma unroll
        for (int j = 0; j < 4; ++j) {
            const float iv = inv_[j];
            #pragma unroll
            for (int i = 0; i < 4; ++i) {
                u16x4 w;
                #pragma unroll
                for (int rr = 0; rr < 4; ++rr) w[rr] = f2b(acc[i][j][rr] * iv);
                *(u16x4*)(P + (j * 16 + r) * 72 + i * 16 + g * 4) = w;
            }
        }
        // PV, operand-swapped: lane owns 4 consecutive d cols
        f32x4 o[2][4] = {};
        #pragma unroll
        for (int ks = 0; ks < 2; ++ks) {
            bf16x8 pa[4], vb[2];
            #pragma unroll
            for (int i = 0; i < 4; ++i)
                pa[i] = *(const bf16x8*)(P + (i * 16 + r) * 72 + ks * 32 + g * 8);
            #pragma unroll
            for (int j = 0; j < 2; ++j)
                vb[j] = *(const bf16x8*)(Vt + (j * 16 + r) * 72 + ks * 32 + g * 8);
            #pragma unroll
            for (int j = 0; j < 2; ++j)
                #pragma unroll
                for (int i = 0; i < 4; ++i)
                    o[j][i] = __builtin_amdgcn_mfma_f32_16x16x32_bf16(vb[j], pa[i], o[j][i], 0, 0, 0);
        }
        u16* op = out + (size_t)win * 64 * 256 + h * 32;
        #pragma unroll
        for (int i = 0; i < 4; ++i) {
            const int qrow = i * 16 + r;
            #pragma unroll
            for (int j = 0; j < 2; ++j) {
                u16x4 w;
                #pragma unroll
                for (int rr = 0; rr < 4; ++rr) w[rr] = f2b(o[j][i][rr]);
                *(u16x4*)(op + (size_t)qrow * 256 + j * 16 + g * 4) = w;
            }
        }
    }
}

// ---------------------------------------------------------------------------
extern "C" void kernel_launch(void* const* d_in, const int* in_sizes, int n_in,
                              void* d_out, int out_size, void* d_ws, size_t ws_size,
                              hipStream_t stream)
{
    (void)in_sizes; (void)n_in; (void)out_size; (void)ws_size;
    const float* x = (const float*)d_in[0];
    char* ws = (char*)d_ws;
    size_t off = 0;
    auto alloc = [&](size_t bytes) { void* p = ws + off; off += (bytes + 255) & ~(size_t)255; return p; };

    u16 *wtq[2], *wto[2], *wt1[2], *wt2[2];
    float* bmT[2];
    for (int i = 0; i < 2; ++i) {
        wtq[i] = (u16*)alloc((size_t)768 * 256 * 2);
        wto[i] = (u16*)alloc((size_t)256 * 256 * 2);
        wt1[i] = (u16*)alloc((size_t)1024 * 256 * 2);
        wt2[i] = (u16*)alloc((size_t)256 * 1024 * 2);
        bmT[i] = (float*)alloc((size_t)4 * 8 * 64 * 64 * 4);
    }
    u16*  xw  = (u16*)alloc((size_t)65536 * 256 * 2);
    u16*  big = (u16*)alloc((size_t)65536 * 768 * 2);
    float* x1 = (float*)alloc((size_t)65536 * 256 * 4);
    float* outp = (float*)d_out;

    for (int blk = 0; blk < 2; ++blk) {
        const float* const* P = (const float* const*)(d_in + 1 + blk * 15);
        transpose_w<<<dim3(768 / 32, 256 / 32), 256, 0, stream>>>(P[2], wtq[blk], 256, 768);
        transpose_w<<<dim3(256 / 32, 256 / 32), 256, 0, stream>>>(P[5], wto[blk], 256, 256);
        transpose_w<<<dim3(1024 / 32, 256 / 32), 256, 0, stream>>>(P[11], wt1[blk], 256, 1024);
        transpose_w<<<dim3(256 / 32, 1024 / 32), 256, 0, stream>>>(P[13], wt2[blk], 1024, 256);
        build_bias<<<512, 256, 0, stream>>>(P[4], bmT[blk]);
    }

    for (int blk = 0; blk < 2; ++blk) {
        const float* const* P = (const float* const*)(d_in + 1 + blk * 15);
        const int sh = blk ? 4 : 0;
        const float* xin = blk ? outp : x;

        ln_win_kernel<<<16384, 256, 0, stream>>>(xin, P[0], P[1], xw, sh);
        gemm_bf16<0><<<dim3(6, 512), 256, 0, stream>>>(xw, wtq[blk], P[3], big, nullptr, 65536, 768, 256, 0);
        if (blk) attn_mfma<1><<<1024, 256, 0, stream>>>(big, bmT[blk], xw);
        else     attn_mfma<0><<<1024, 256, 0, stream>>>(big, bmT[blk], xw);
        gemm_bf16<2><<<dim3(2, 512), 256, 0, stream>>>(xw, wto[blk], P[6], x1, xin, 65536, 256, 256, sh);
        ln2_kernel<<<16384, 256, 0, stream>>>(x1, P[7], P[8], P[9], P[10], xw);
        fused_mlp<<<1024, 512, 0, stream>>>(xw, wt1[blk], P[12], wt2[blk], P[14], x1, outp);
    }
}

// Round 5
// 739.247 us; speedup vs baseline: 1.2433x; 1.0853x over previous
//
#include <hip/hip_runtime.h>

typedef unsigned short u16;
typedef __attribute__((ext_vector_type(8))) short bf16x8;
typedef __attribute__((ext_vector_type(8))) unsigned short u16x8;
typedef __attribute__((ext_vector_type(4))) unsigned short u16x4;
typedef __attribute__((ext_vector_type(4))) float f32x4;

__device__ inline float b2f(u16 u) {
    union { unsigned u32; float f; } x; x.u32 = ((unsigned)u) << 16; return x.f;
}
__device__ inline u16 f2b(float f) {
    union { float f; unsigned u; } x; x.f = f;
    unsigned r = x.u + 0x7fffu + ((x.u >> 16) & 1u);
    return (u16)(r >> 16);
}

// fast exact-erf GELU (A&S 7.1.26, |err|<1.5e-7)
__device__ inline float fast_gelu(float v) {
    float x = fabsf(v) * 0.70710678118654752f;
    float t = __builtin_amdgcn_rcpf(1.0f + 0.3275911f * x);
    float e = __expf(-x * x);
    float poly = ((((1.061405429f * t - 1.453152027f) * t + 1.421413741f) * t
                   - 0.284496736f) * t + 0.254829592f) * t;
    float erfv = 1.0f - poly * e;
    float w = copysignf(erfv, v);
    return 0.5f * v * (1.0f + w);
}

#define GLOAD_LDS16(g, l) \
    __builtin_amdgcn_global_load_lds((const __attribute__((address_space(1))) void*)(const void*)(g), \
                                     (__attribute__((address_space(3))) void*)(void*)(l), 16, 0, 0)
#define FENCE() asm volatile("" ::: "memory")

// ---------------- LN1 + shift + window partition -> bf16 ----------------
__global__ __launch_bounds__(256)
void ln_win_kernel(const float* __restrict__ x, const float* __restrict__ g,
                   const float* __restrict__ b, u16* __restrict__ xw, int shift)
{
    int wid = blockIdx.x * 4 + (threadIdx.x >> 6);
    int lane = threadIdx.x & 63;
    int win = wid >> 6, tok = wid & 63;
    int bb = win >> 6, wib = win & 63;
    int h = (((wib >> 3) << 3) + (tok >> 3) + shift) & 63;
    int w = (((wib & 7) << 3) + (tok & 7) + shift) & 63;
    size_t src = ((size_t)bb * 4096 + h * 64 + w) * 256;
    float4 v = ((const float4*)(x + src))[lane];
    float s = v.x + v.y + v.z + v.w;
    float s2 = v.x*v.x + v.y*v.y + v.z*v.z + v.w*v.w;
    for (int k = 32; k > 0; k >>= 1) { s += __shfl_xor(s, k); s2 += __shfl_xor(s2, k); }
    float mean = s * (1.f/256.f);
    float var  = s2 * (1.f/256.f) - mean*mean;
    float rs = rsqrtf(var + 1e-5f);
    int c = lane * 4;
    u16x4 o;
    o[0] = f2b((v.x - mean) * rs * g[c+0] + b[c+0]);
    o[1] = f2b((v.y - mean) * rs * g[c+1] + b[c+1]);
    o[2] = f2b((v.z - mean) * rs * g[c+2] + b[c+2]);
    o[3] = f2b((v.w - mean) * rs * g[c+3] + b[c+3]);
    *(u16x4*)(xw + (size_t)wid * 256 + c) = o;
}

// ---------------- fused LN2(1e-5) then LN3(1e-6) -> bf16 -------------------
__global__ __launch_bounds__(256)
void ln2_kernel(const float* __restrict__ xin,
                const float* __restrict__ g1, const float* __restrict__ b1,
                const float* __restrict__ g2, const float* __restrict__ b2,
                u16* __restrict__ out)
{
    int wid = blockIdx.x * 4 + (threadIdx.x >> 6);
    int lane = threadIdx.x & 63;
    float4 v = ((const float4*)(xin + (size_t)wid * 256))[lane];
    float s = v.x + v.y + v.z + v.w;
    float s2 = v.x*v.x + v.y*v.y + v.z*v.z + v.w*v.w;
    for (int k = 32; k > 0; k >>= 1) { s += __shfl_xor(s, k); s2 += __shfl_xor(s2, k); }
    float mean = s * (1.f/256.f);
    float var  = s2 * (1.f/256.f) - mean*mean;
    float rs = rsqrtf(var + 1e-5f);
    int c = lane * 4;
    float y0 = (v.x - mean) * rs * g1[c+0] + b1[c+0];
    float y1 = (v.y - mean) * rs * g1[c+1] + b1[c+1];
    float y2 = (v.z - mean) * rs * g1[c+2] + b1[c+2];
    float y3 = (v.w - mean) * rs * g1[c+3] + b1[c+3];
    float t = y0 + y1 + y2 + y3;
    float t2 = y0*y0 + y1*y1 + y2*y2 + y3*y3;
    for (int k = 32; k > 0; k >>= 1) { t += __shfl_xor(t, k); t2 += __shfl_xor(t2, k); }
    float m2 = t * (1.f/256.f);
    float v2 = t2 * (1.f/256.f) - m2*m2;
    float rs2 = rsqrtf(v2 + 1e-6f);
    u16x4 o;
    o[0] = f2b((y0 - m2) * rs2 * g2[c+0] + b2[c+0]);
    o[1] = f2b((y1 - m2) * rs2 * g2[c+1] + b2[c+1]);
    o[2] = f2b((y2 - m2) * rs2 * g2[c+2] + b2[c+2]);
    o[3] = f2b((y3 - m2) * rs2 * g2[c+3] + b2[c+3]);
    *(u16x4*)(out + (size_t)wid * 256 + c) = o;
}

// ---------------- weight transpose f32[K][N] -> bf16 Wt[N][K] --------------
__global__ __launch_bounds__(256)
void transpose_w(const float* __restrict__ W, u16* __restrict__ Wt, int K, int N)
{
    __shared__ float t[32][33];
    int nb = blockIdx.x * 32, kb = blockIdx.y * 32;
    int tx = threadIdx.x & 31, ty = threadIdx.x >> 5;
    #pragma unroll
    for (int r = 0; r < 32; r += 8)
        t[ty + r][tx] = W[(size_t)(kb + ty + r) * N + nb + tx];
    __syncthreads();
    #pragma unroll
    for (int r = 0; r < 32; r += 8)
        Wt[(size_t)(nb + ty + r) * K + kb + tx] = f2b(t[tx][ty + r]);
}

// ---------------- bias(+mask) table: bmT[cls][h][k][q] * log2e -------------
__global__ __launch_bounds__(256)
void build_bias(const float* __restrict__ rpb, float* __restrict__ bmT)
{
    int idx = blockIdx.x * 256 + threadIdx.x;      // 4*8*64*64 = 131072
    int q = idx & 63, k = (idx >> 6) & 63, h = (idx >> 12) & 7, cls = idx >> 15;
    int qh = q >> 3, qw = q & 7, kh = k >> 3, kw = k & 7;
    float v = rpb[((qh - kh + 7) * 15 + (qw - kw + 7)) * 8 + h];
    int ch = cls >> 1, cw = cls & 1;
    int rq = (ch ? (qh < 4 ? 1 : 2) : 0) * 3 + (cw ? (qw < 4 ? 1 : 2) : 0);
    int rk = (ch ? (kh < 4 ? 1 : 2) : 0) * 3 + (cw ? (kw < 4 ? 1 : 2) : 0);
    if (rq != rk) v -= 100.f;
    bmT[idx] = v * 1.4426950408889634f;
}

// ======== K=256 GEMM, B-panel LDS-resident, counted-vmcnt pipeline =========
// Block: 4 waves, 128x128 tile, RT=2 row-tiles reusing the resident B panel.
// B stored as 8 k-chunks [128][32] (bank-minimal ds_read_b128).
// EPI 0: bf16+bias; EPI 1: gelu->bf16; EPI 2: f32 winrev+residual.
template<int EPI>
__global__ __launch_bounds__(256)
void gemm_bres(const u16* __restrict__ A, const u16* __restrict__ Bt,
               const float* __restrict__ bias, void* __restrict__ out,
               const float* __restrict__ resid, int M, int N, int shift)
{
    constexpr int K = 256, RT = 2;
    __shared__ u16 Bs[8][128][32];   // 64 KB resident weight panel
    __shared__ u16 As[2][128][32];   // 16 KB A double-buffer
    const int tid = threadIdx.x, lane = tid & 63, wv = tid >> 6;
    const int g = lane >> 4, r = lane & 15;
    const int wr = wv >> 1, wc = wv & 1;
    // T1 XCD-chunked bijective swizzle
    const int nwg = gridDim.x * gridDim.y;
    const int lid = blockIdx.y * gridDim.x + blockIdx.x;
    const int qq = nwg >> 3, r8 = nwg & 7;
    const int xcd = lid & 7, pos = lid >> 3;
    const int nid = (xcd < r8 ? xcd * (qq + 1) : r8 * (qq + 1) + (xcd - r8) * qq) + pos;
    const int bm_grp = nid / gridDim.x, bn = nid % gridDim.x;

    // ---- stage resident B panel: LDS[c][row][col] = Bt[bn*128+row][c*32+col]
    const u16* Bp = Bt + (size_t)bn * 128 * K;
    #pragma unroll
    for (int it = 0; it < 16; ++it) {
        const int L8 = it * 256 + tid;
        const int src = ((L8 >> 2) & 127) * K + (L8 >> 9) * 32 + (L8 & 3) * 8;
        GLOAD_LDS16(Bp + src, &Bs[0][0][0] + (size_t)(it * 256 + wv * 64) * 8);
    }
    const int arow = wv * 16 + (lane >> 2);
    const int acol = (lane & 3) * 8;
    const u16* gA0 = A + ((size_t)(bm_grp * RT) * 128 + arow) * K + acol;

    for (int rt = 0; rt < RT; ++rt) {
        const u16* gA = gA0 + (size_t)rt * 128 * K;
        // prologue: stage k-tile 0 into buf0, full drain (also covers B panel)
        GLOAD_LDS16(gA,          &As[0][0][0] + wv * 512);
        GLOAD_LDS16(gA + 64 * K, &As[0][0][0] + 2048 + wv * 512);
        f32x4 acc[4][4] = {};   // [j=col frag][i=row frag]
        asm volatile("s_waitcnt vmcnt(0)" ::: "memory");
        __builtin_amdgcn_s_barrier();
        FENCE();
        #pragma unroll
        for (int kt = 0; kt < 8; ++kt) {
            const int cur = kt & 1;
            if (kt < 7) {
                GLOAD_LDS16(gA + (kt + 1) * 32,          &As[cur ^ 1][0][0] + wv * 512);
                GLOAD_LDS16(gA + (kt + 1) * 32 + 64 * K, &As[cur ^ 1][0][0] + 2048 + wv * 512);
                asm volatile("s_waitcnt vmcnt(2)" ::: "memory");   // cur landed; next in flight
            } else {
                asm volatile("s_waitcnt vmcnt(0)" ::: "memory");
            }
            __builtin_amdgcn_s_barrier();
            FENCE();
            bf16x8 af[4], bf[4];
            #pragma unroll
            for (int i = 0; i < 4; ++i)
                af[i] = *(const bf16x8*)(&As[cur][wr * 64 + i * 16 + r][g * 8]);
            #pragma unroll
            for (int j = 0; j < 4; ++j)
                bf[j] = *(const bf16x8*)(&Bs[kt][wc * 64 + j * 16 + r][g * 8]);
            #pragma unroll
            for (int j = 0; j < 4; ++j)
                #pragma unroll
                for (int i = 0; i < 4; ++i)
                    acc[j][i] = __builtin_amdgcn_mfma_f32_16x16x32_bf16(bf[j], af[i], acc[j][i], 0, 0, 0);
            asm volatile("s_waitcnt lgkmcnt(0)" ::: "memory");
            __builtin_amdgcn_sched_barrier(0);
            __builtin_amdgcn_s_barrier();
            FENCE();
        }
        // ---- epilogue
        #pragma unroll
        for (int i = 0; i < 4; ++i) {
            const int row = (bm_grp * RT + rt) * 128 + wr * 64 + i * 16 + r;
            size_t orow;
            if (EPI == 2) {
                int win = row >> 6, tok = row & 63;
                int bb = win >> 6, wib = win & 63;
                int h = (((wib >> 3) << 3) + (tok >> 3) + shift) & 63;
                int w = (((wib & 7) << 3) + (tok & 7) + shift) & 63;
                orow = (size_t)bb * 4096 + h * 64 + w;
            } else {
                orow = (size_t)row;
            }
            #pragma unroll
            for (int j = 0; j < 4; ++j) {
                const int colb = bn * 128 + wc * 64 + j * 16 + g * 4;
                const float4 bv = *(const float4*)(bias + colb);
                if (EPI == 0) {
                    u16x4 o;
                    o[0] = f2b(acc[j][i][0] + bv.x);
                    o[1] = f2b(acc[j][i][1] + bv.y);
                    o[2] = f2b(acc[j][i][2] + bv.z);
                    o[3] = f2b(acc[j][i][3] + bv.w);
                    *(u16x4*)((u16*)out + (size_t)row * N + colb) = o;
                } else if (EPI == 1) {
                    u16x4 o;
                    o[0] = f2b(fast_gelu(acc[j][i][0] + bv.x));
                    o[1] = f2b(fast_gelu(acc[j][i][1] + bv.y));
                    o[2] = f2b(fast_gelu(acc[j][i][2] + bv.z));
                    o[3] = f2b(fast_gelu(acc[j][i][3] + bv.w));
                    *(u16x4*)((u16*)out + (size_t)row * N + colb) = o;
                } else {
                    const float4 rv = *(const float4*)(resid + orow * N + colb);
                    float4 o;
                    o.x = rv.x + acc[j][i][0] + bv.x;
                    o.y = rv.y + acc[j][i][1] + bv.y;
                    o.z = rv.z + acc[j][i][2] + bv.z;
                    o.w = rv.w + acc[j][i][3] + bv.w;
                    *(float4*)((float*)out + orow * N + colb) = o;
                }
            }
        }
    }
}

// ======== general-K 128x128 GEMM, dbuf A+B, counted-vmcnt pipeline =========
// EPI 3: f32 store + residual add (identity rows)
template<int EPI>
__global__ __launch_bounds__(256)
void gemm_dbuf(const u16* __restrict__ A, const u16* __restrict__ Bt,
               const float* __restrict__ bias, void* __restrict__ out,
               const float* __restrict__ resid, int M, int N, int K)
{
    __shared__ u16 As[2][128][32];
    __shared__ u16 Bs[2][128][32];
    const int tid = threadIdx.x, lane = tid & 63, wv = tid >> 6;
    const int g = lane >> 4, r = lane & 15;
    const int wr = wv >> 1, wc = wv & 1;
    const int nwg = gridDim.x * gridDim.y;
    const int lid = blockIdx.y * gridDim.x + blockIdx.x;
    const int qq = nwg >> 3, r8 = nwg & 7;
    const int xcd = lid & 7, pos = lid >> 3;
    const int nid = (xcd < r8 ? xcd * (qq + 1) : r8 * (qq + 1) + (xcd - r8) * qq) + pos;
    const int bm = nid / gridDim.x, bn = nid % gridDim.x;
    f32x4 acc[4][4] = {};
    const int arow = wv * 16 + (lane >> 2);
    const int acol = (lane & 3) * 8;
    const u16* gA = A + (size_t)(bm * 128 + arow) * K + acol;
    const u16* gB = Bt + (size_t)(bn * 128 + arow) * K + acol;
    const int nk = K >> 5;
    GLOAD_LDS16(gA,          &As[0][0][0] + wv * 512);
    GLOAD_LDS16(gA + 64 * K, &As[0][0][0] + 2048 + wv * 512);
    GLOAD_LDS16(gB,          &Bs[0][0][0] + wv * 512);
    GLOAD_LDS16(gB + 64 * K, &Bs[0][0][0] + 2048 + wv * 512);
    gA += 32; gB += 32;
    asm volatile("s_waitcnt vmcnt(0)" ::: "memory");
    __builtin_amdgcn_s_barrier();
    FENCE();
    for (int kt = 0; kt < nk; ++kt) {
        const int cur = kt & 1;
        if (kt + 1 < nk) {
            GLOAD_LDS16(gA,          &As[cur ^ 1][0][0] + wv * 512);
            GLOAD_LDS16(gA + 64 * K, &As[cur ^ 1][0][0] + 2048 + wv * 512);
            GLOAD_LDS16(gB,          &Bs[cur ^ 1][0][0] + wv * 512);
            GLOAD_LDS16(gB + 64 * K, &Bs[cur ^ 1][0][0] + 2048 + wv * 512);
            gA += 32; gB += 32;
            asm volatile("s_waitcnt vmcnt(4)" ::: "memory");
        } else {
            asm volatile("s_waitcnt vmcnt(0)" ::: "memory");
        }
        __builtin_amdgcn_s_barrier();
        FENCE();
        bf16x8 af[4], bf[4];
        #pragma unroll
        for (int i = 0; i < 4; ++i)
            af[i] = *(const bf16x8*)(&As[cur][wr * 64 + i * 16 + r][g * 8]);
        #pragma unroll
        for (int j = 0; j < 4; ++j)
            bf[j] = *(const bf16x8*)(&Bs[cur][wc * 64 + j * 16 + r][g * 8]);
        #pragma unroll
        for (int j = 0; j < 4; ++j)
            #pragma unroll
            for (int i = 0; i < 4; ++i)
                acc[j][i] = __builtin_amdgcn_mfma_f32_16x16x32_bf16(bf[j], af[i], acc[j][i], 0, 0, 0);
        asm volatile("s_waitcnt lgkmcnt(0)" ::: "memory");
        __builtin_amdgcn_sched_barrier(0);
        __builtin_amdgcn_s_barrier();
        FENCE();
    }
    #pragma unroll
    for (int i = 0; i < 4; ++i) {
        const int row = bm * 128 + wr * 64 + i * 16 + r;
        #pragma unroll
        for (int j = 0; j < 4; ++j) {
            const int colb = bn * 128 + wc * 64 + j * 16 + g * 4;
            const float4 bv = *(const float4*)(bias + colb);
            const float4 rv = *(const float4*)(resid + (size_t)row * N + colb);
            float4 o;
            o.x = rv.x + acc[j][i][0] + bv.x;
            o.y = rv.y + acc[j][i][1] + bv.y;
            o.z = rv.z + acc[j][i][2] + bv.z;
            o.w = rv.w + acc[j][i][3] + bv.w;
            *(float4*)((float*)out + (size_t)row * N + colb) = o;
        }
    }
}

// ---------------- MFMA attention: one block per window, wave = 2 heads -----
template<int SHIFTED>
__global__ __launch_bounds__(256)
void attn_mfma(const u16* __restrict__ qkv, const float* __restrict__ bmT,
               u16* __restrict__ out)
{
    __shared__ u16 pbuf[4][64 * 72];
    __shared__ u16 vbuf[4][32 * 72];
    const int tid = threadIdx.x, lane = tid & 63, wv = tid >> 6;
    const int g = lane >> 4, r = lane & 15;
    const int win = blockIdx.x;
    u16* P  = pbuf[wv];
    u16* Vt = vbuf[wv];
    const u16* base = qkv + (size_t)win * 64 * 768;
    int cls = 0;
    if (SHIFTED) {
        int wib = win & 63;
        cls = (((wib >> 3) == 7) ? 2 : 0) + (((wib & 7) == 7) ? 1 : 0);
    }
    const float sc = 0.17677669529663687f * 1.4426950408889634f;

    for (int hh = 0; hh < 2; ++hh) {
        const int h = wv * 2 + hh;
        const float* bmh = bmT + ((size_t)cls * 8 + h) * 4096;
        bf16x8 kf[4], qf[4];
        #pragma unroll
        for (int i = 0; i < 4; ++i) {
            kf[i] = *(const bf16x8*)(base + (size_t)(i * 16 + r) * 768 + 256 + h * 32 + g * 8);
            qf[i] = *(const bf16x8*)(base + (size_t)(i * 16 + r) * 768 +       h * 32 + g * 8);
        }
        #pragma unroll
        for (int d0 = 0; d0 < 32; d0 += 8) {
            u16x8 vv = *(const u16x8*)(base + (size_t)lane * 768 + 512 + h * 32 + d0);
            #pragma unroll
            for (int e = 0; e < 8; ++e) Vt[(d0 + e) * 72 + lane] = vv[e];
        }
        f32x4 acc[4][4] = {};
        #pragma unroll
        for (int i = 0; i < 4; ++i)
            #pragma unroll
            for (int j = 0; j < 4; ++j)
                acc[i][j] = __builtin_amdgcn_mfma_f32_16x16x32_bf16(kf[i], qf[j], acc[i][j], 0, 0, 0);
        #pragma unroll
        for (int i = 0; i < 4; ++i) {
            const int kb = (i * 16 + g * 4) * 64;
            #pragma unroll
            for (int j = 0; j < 4; ++j) {
                const int qq = j * 16 + r;
                #pragma unroll
                for (int rr = 0; rr < 4; ++rr)
                    acc[i][j][rr] = acc[i][j][rr] * sc + bmh[kb + rr * 64 + qq];
            }
        }
        float inv_[4];
        #pragma unroll
        for (int j = 0; j < 4; ++j) {
            float m = acc[0][j][0];
            #pragma unroll
            for (int i = 0; i < 4; ++i)
                #pragma unroll
                for (int rr = 0; rr < 4; ++rr) m = fmaxf(m, acc[i][j][rr]);
            m = fmaxf(m, __shfl_xor(m, 16));
            m = fmaxf(m, __shfl_xor(m, 32));
            float s = 0.f;
            #pragma unroll
            for (int i = 0; i < 4; ++i)
                #pragma unroll
                for (int rr = 0; rr < 4; ++rr) {
                    float p = exp2f(acc[i][j][rr] - m);
                    acc[i][j][rr] = p; s += p;
                }
            s += __shfl_xor(s, 16);
            s += __shfl_xor(s, 32);
            inv_[j] = 1.f / s;
        }
        #pragma unroll
        for (int j = 0; j < 4; ++j) {
            const float iv = inv_[j];
            #pragma unroll
            for (int i = 0; i < 4; ++i) {
                u16x4 w;
                #pragma unroll
                for (int rr = 0; rr < 4; ++rr) w[rr] = f2b(acc[i][j][rr] * iv);
                *(u16x4*)(P + (j * 16 + r) * 72 + i * 16 + g * 4) = w;
            }
        }
        f32x4 o[2][4] = {};
        #pragma unroll
        for (int ks = 0; ks < 2; ++ks) {
            bf16x8 pa[4], vb[2];
            #pragma unroll
            for (int i = 0; i < 4; ++i)
                pa[i] = *(const bf16x8*)(P + (i * 16 + r) * 72 + ks * 32 + g * 8);
            #pragma unroll
            for (int j = 0; j < 2; ++j)
                vb[j] = *(const bf16x8*)(Vt + (j * 16 + r) * 72 + ks * 32 + g * 8);
            #pragma unroll
            for (int j = 0; j < 2; ++j)
                #pragma unroll
                for (int i = 0; i < 4; ++i)
                    o[j][i] = __builtin_amdgcn_mfma_f32_16x16x32_bf16(vb[j], pa[i], o[j][i], 0, 0, 0);
        }
        u16* op = out + (size_t)win * 64 * 256 + h * 32;
        #pragma unroll
        for (int i = 0; i < 4; ++i) {
            const int qrow = i * 16 + r;
            #pragma unroll
            for (int j = 0; j < 2; ++j) {
                u16x4 w;
                #pragma unroll
                for (int rr = 0; rr < 4; ++rr) w[rr] = f2b(o[j][i][rr]);
                *(u16x4*)(op + (size_t)qrow * 256 + j * 16 + g * 4) = w;
            }
        }
    }
}

// ---------------------------------------------------------------------------
extern "C" void kernel_launch(void* const* d_in, const int* in_sizes, int n_in,
                              void* d_out, int out_size, void* d_ws, size_t ws_size,
                              hipStream_t stream)
{
    (void)in_sizes; (void)n_in; (void)out_size; (void)ws_size;
    const float* x = (const float*)d_in[0];
    char* ws = (char*)d_ws;
    size_t off = 0;
    auto alloc = [&](size_t bytes) { void* p = ws + off; off += (bytes + 255) & ~(size_t)255; return p; };

    u16 *wtq[2], *wto[2], *wt1[2], *wt2[2];
    float* bmT[2];
    for (int i = 0; i < 2; ++i) {
        wtq[i] = (u16*)alloc((size_t)768 * 256 * 2);
        wto[i] = (u16*)alloc((size_t)256 * 256 * 2);
        wt1[i] = (u16*)alloc((size_t)1024 * 256 * 2);
        wt2[i] = (u16*)alloc((size_t)256 * 1024 * 2);
        bmT[i] = (float*)alloc((size_t)4 * 8 * 64 * 64 * 4);
    }
    u16*  xw  = (u16*)alloc((size_t)65536 * 256 * 2);
    u16*  big = (u16*)alloc((size_t)65536 * 1024 * 2);
    float* x1 = (float*)alloc((size_t)65536 * 256 * 4);
    float* outp = (float*)d_out;

    for (int blk = 0; blk < 2; ++blk) {
        const float* const* P = (const float* const*)(d_in + 1 + blk * 15);
        transpose_w<<<dim3(768 / 32, 256 / 32), 256, 0, stream>>>(P[2], wtq[blk], 256, 768);
        transpose_w<<<dim3(256 / 32, 256 / 32), 256, 0, stream>>>(P[5], wto[blk], 256, 256);
        transpose_w<<<dim3(1024 / 32, 256 / 32), 256, 0, stream>>>(P[11], wt1[blk], 256, 1024);
        transpose_w<<<dim3(256 / 32, 1024 / 32), 256, 0, stream>>>(P[13], wt2[blk], 1024, 256);
        build_bias<<<512, 256, 0, stream>>>(P[4], bmT[blk]);
    }

    for (int blk = 0; blk < 2; ++blk) {
        const float* const* P = (const float* const*)(d_in + 1 + blk * 15);
        const int sh = blk ? 4 : 0;
        const float* xin = blk ? outp : x;

        ln_win_kernel<<<16384, 256, 0, stream>>>(xin, P[0], P[1], xw, sh);
        gemm_bres<0><<<dim3(6, 256), 256, 0, stream>>>(xw, wtq[blk], P[3], big, nullptr, 65536, 768, 0);
        if (blk) attn_mfma<1><<<1024, 256, 0, stream>>>(big, bmT[blk], xw);
        else     attn_mfma<0><<<1024, 256, 0, stream>>>(big, bmT[blk], xw);
        gemm_bres<2><<<dim3(2, 256), 256, 0, stream>>>(xw, wto[blk], P[6], x1, xin, 65536, 256, sh);
        ln2_kernel<<<16384, 256, 0, stream>>>(x1, P[7], P[8], P[9], P[10], xw);
        gemm_bres<1><<<dim3(8, 256), 256, 0, stream>>>(xw, wt1[blk], P[12], big, nullptr, 65536, 1024, 0);
        gemm_dbuf<3><<<dim3(2, 512), 256, 0, stream>>>(big, wt2[blk], P[14], outp, x1, 65536, 256, 1024);
    }
}

// Round 6
// 723.060 us; speedup vs baseline: 1.2711x; 1.0224x over previous
//
#include <hip/hip_runtime.h>

typedef unsigned short u16;
typedef __attribute__((ext_vector_type(8))) short bf16x8;
typedef __attribute__((ext_vector_type(8))) unsigned short u16x8;
typedef __attribute__((ext_vector_type(4))) unsigned short u16x4;
typedef __attribute__((ext_vector_type(4))) float f32x4;

__device__ inline float b2f(u16 u) {
    union { unsigned u32; float f; } x; x.u32 = ((unsigned)u) << 16; return x.f;
}
__device__ inline u16 f2b(float f) {
    union { float f; unsigned u; } x; x.f = f;
    unsigned r = x.u + 0x7fffu + ((x.u >> 16) & 1u);
    return (u16)(r >> 16);
}

// fast exact-erf GELU (A&S 7.1.26, |err|<1.5e-7)
__device__ inline float fast_gelu(float v) {
    float x = fabsf(v) * 0.70710678118654752f;
    float t = __builtin_amdgcn_rcpf(1.0f + 0.3275911f * x);
    float e = __expf(-x * x);
    float poly = ((((1.061405429f * t - 1.453152027f) * t + 1.421413741f) * t
                   - 0.284496736f) * t + 0.254829592f) * t;
    float erfv = 1.0f - poly * e;
    float w = copysignf(erfv, v);
    return 0.5f * v * (1.0f + w);
}

#define GLOAD_LDS16(g, l) \
    __builtin_amdgcn_global_load_lds((const __attribute__((address_space(1))) void*)(const void*)(g), \
                                     (__attribute__((address_space(3))) void*)(void*)(l), 16, 0, 0)
#define FENCE() asm volatile("" ::: "memory")

// ---------------- LN1 + shift + window partition -> bf16 ----------------
__global__ __launch_bounds__(256)
void ln_win_kernel(const float* __restrict__ x, const float* __restrict__ g,
                   const float* __restrict__ b, u16* __restrict__ xw, int shift)
{
    int wid = blockIdx.x * 4 + (threadIdx.x >> 6);
    int lane = threadIdx.x & 63;
    int win = wid >> 6, tok = wid & 63;
    int bb = win >> 6, wib = win & 63;
    int h = (((wib >> 3) << 3) + (tok >> 3) + shift) & 63;
    int w = (((wib & 7) << 3) + (tok & 7) + shift) & 63;
    size_t src = ((size_t)bb * 4096 + h * 64 + w) * 256;
    float4 v = ((const float4*)(x + src))[lane];
    float s = v.x + v.y + v.z + v.w;
    float s2 = v.x*v.x + v.y*v.y + v.z*v.z + v.w*v.w;
    for (int k = 32; k > 0; k >>= 1) { s += __shfl_xor(s, k); s2 += __shfl_xor(s2, k); }
    float mean = s * (1.f/256.f);
    float var  = s2 * (1.f/256.f) - mean*mean;
    float rs = rsqrtf(var + 1e-5f);
    int c = lane * 4;
    u16x4 o;
    o[0] = f2b((v.x - mean) * rs * g[c+0] + b[c+0]);
    o[1] = f2b((v.y - mean) * rs * g[c+1] + b[c+1]);
    o[2] = f2b((v.z - mean) * rs * g[c+2] + b[c+2]);
    o[3] = f2b((v.w - mean) * rs * g[c+3] + b[c+3]);
    *(u16x4*)(xw + (size_t)wid * 256 + c) = o;
}

// ---------------- fused LN2(1e-5) then LN3(1e-6) -> bf16 -------------------
__global__ __launch_bounds__(256)
void ln2_kernel(const float* __restrict__ xin,
                const float* __restrict__ g1, const float* __restrict__ b1,
                const float* __restrict__ g2, const float* __restrict__ b2,
                u16* __restrict__ out)
{
    int wid = blockIdx.x * 4 + (threadIdx.x >> 6);
    int lane = threadIdx.x & 63;
    float4 v = ((const float4*)(xin + (size_t)wid * 256))[lane];
    float s = v.x + v.y + v.z + v.w;
    float s2 = v.x*v.x + v.y*v.y + v.z*v.z + v.w*v.w;
    for (int k = 32; k > 0; k >>= 1) { s += __shfl_xor(s, k); s2 += __shfl_xor(s2, k); }
    float mean = s * (1.f/256.f);
    float var  = s2 * (1.f/256.f) - mean*mean;
    float rs = rsqrtf(var + 1e-5f);
    int c = lane * 4;
    float y0 = (v.x - mean) * rs * g1[c+0] + b1[c+0];
    float y1 = (v.y - mean) * rs * g1[c+1] + b1[c+1];
    float y2 = (v.z - mean) * rs * g1[c+2] + b1[c+2];
    float y3 = (v.w - mean) * rs * g1[c+3] + b1[c+3];
    float t = y0 + y1 + y2 + y3;
    float t2 = y0*y0 + y1*y1 + y2*y2 + y3*y3;
    for (int k = 32; k > 0; k >>= 1) { t += __shfl_xor(t, k); t2 += __shfl_xor(t2, k); }
    float m2 = t * (1.f/256.f);
    float v2 = t2 * (1.f/256.f) - m2*m2;
    float rs2 = rsqrtf(v2 + 1e-6f);
    u16x4 o;
    o[0] = f2b((y0 - m2) * rs2 * g2[c+0] + b2[c+0]);
    o[1] = f2b((y1 - m2) * rs2 * g2[c+1] + b2[c+1]);
    o[2] = f2b((y2 - m2) * rs2 * g2[c+2] + b2[c+2]);
    o[3] = f2b((y3 - m2) * rs2 * g2[c+3] + b2[c+3]);
    *(u16x4*)(out + (size_t)wid * 256 + c) = o;
}

// ---------------- weight transpose f32[K][N] -> bf16 Wt[N][K] --------------
__global__ __launch_bounds__(256)
void transpose_w(const float* __restrict__ W, u16* __restrict__ Wt, int K, int N)
{
    __shared__ float t[32][33];
    int nb = blockIdx.x * 32, kb = blockIdx.y * 32;
    int tx = threadIdx.x & 31, ty = threadIdx.x >> 5;
    #pragma unroll
    for (int r = 0; r < 32; r += 8)
        t[ty + r][tx] = W[(size_t)(kb + ty + r) * N + nb + tx];
    __syncthreads();
    #pragma unroll
    for (int r = 0; r < 32; r += 8)
        Wt[(size_t)(nb + ty + r) * K + kb + tx] = f2b(t[tx][ty + r]);
}

// ---------------- bias(+mask) table: bmT[cls][h][k][q] * log2e -------------
__global__ __launch_bounds__(256)
void build_bias(const float* __restrict__ rpb, float* __restrict__ bmT)
{
    int idx = blockIdx.x * 256 + threadIdx.x;      // 4*8*64*64 = 131072
    int q = idx & 63, k = (idx >> 6) & 63, h = (idx >> 12) & 7, cls = idx >> 15;
    int qh = q >> 3, qw = q & 7, kh = k >> 3, kw = k & 7;
    float v = rpb[((qh - kh + 7) * 15 + (qw - kw + 7)) * 8 + h];
    int ch = cls >> 1, cw = cls & 1;
    int rq = (ch ? (qh < 4 ? 1 : 2) : 0) * 3 + (cw ? (qw < 4 ? 1 : 2) : 0);
    int rk = (ch ? (kh < 4 ? 1 : 2) : 0) * 3 + (cw ? (kw < 4 ? 1 : 2) : 0);
    if (rq != rk) v -= 100.f;
    bmT[idx] = v * 1.4426950408889634f;
}

// ======== unified 128x128 GEMM: 4-buf, depth-2 prefetch, 1 barrier/iter ====
// LDS XOR-swizzle via pre-swizzled global source (both-sides, rule 21).
// EPI 0: bf16+bias; EPI 1: gelu->bf16; EPI 2: f32 winrev+residual;
// EPI 3: f32 +residual (identity rows).
template<int EPI>
__global__ __launch_bounds__(256)
void gemm_k4(const u16* __restrict__ A, const u16* __restrict__ Bt,
             const float* __restrict__ bias, void* __restrict__ out,
             const float* __restrict__ resid, int M, int N, int K, int shift)
{
    __shared__ u16 As[4][128][32];   // 32 KB
    __shared__ u16 Bs[4][128][32];   // 32 KB
    const int tid = threadIdx.x, lane = tid & 63, wv = tid >> 6;
    const int g = lane >> 4, r = lane & 15;
    const int wr = wv >> 1, wc = wv & 1;
    // T1 XCD-chunked bijective swizzle
    const int nwg = gridDim.x * gridDim.y;
    const int lid = blockIdx.y * gridDim.x + blockIdx.x;
    const int qq = nwg >> 3, r8 = nwg & 7;
    const int xcd = lid & 7, pos = lid >> 3;
    const int nid = (xcd < r8 ? xcd * (qq + 1) : r8 * (qq + 1) + (xcd - r8) * qq) + pos;
    const int bm = nid / gridDim.x, bn = nid % gridDim.x;

    f32x4 acc[4][4] = {};   // [j=col frag][i=row frag]
    // staging: lane writes LDS row (wv*16 + lane>>2)(+64), 16B slot lane&3 (linear).
    // pre-swizzled SOURCE col so LDS slot c8 holds A[row][c8 ^ swz(row)],
    // swz(row) = (row&3) ^ ((row>>2)&1).
    const int arow = wv * 16 + (lane >> 2);
    const int scol = (((lane & 3) ^ ((lane >> 2) & 3) ^ ((lane >> 4) & 1)) * 8);
    const u16* gA = A + (size_t)(bm * 128 + arow) * K + scol;
    const u16* gB = Bt + (size_t)(bn * 128 + arow) * K + scol;
    const int nk = K >> 5;
    // swizzled READ col (row bits == r bits for all fragment rows)
    const int rc = (g ^ (r & 3) ^ ((r >> 2) & 1)) * 8;

#define STAGE(t) do { \
        u16* a_ = &As[(t) & 3][0][0]; u16* b_ = &Bs[(t) & 3][0][0]; \
        GLOAD_LDS16(gA + (size_t)(t) * 32,                    a_ + wv * 512); \
        GLOAD_LDS16(gA + (size_t)(t) * 32 + (size_t)64 * K,   a_ + 2048 + wv * 512); \
        GLOAD_LDS16(gB + (size_t)(t) * 32,                    b_ + wv * 512); \
        GLOAD_LDS16(gB + (size_t)(t) * 32 + (size_t)64 * K,   b_ + 2048 + wv * 512); \
    } while (0)

    STAGE(0);
    STAGE(1);
    for (int kt = 0; kt < nk; ++kt) {
        const int cur = kt & 3;
        if (kt + 2 < nk) {
            STAGE(kt + 2);
            asm volatile("s_waitcnt vmcnt(8)" ::: "memory");   // tile kt landed; kt+1,kt+2 in flight
        } else if (kt + 1 < nk) {
            asm volatile("s_waitcnt vmcnt(4)" ::: "memory");
        } else {
            asm volatile("s_waitcnt vmcnt(0)" ::: "memory");
        }
        __builtin_amdgcn_s_barrier();
        FENCE();
        bf16x8 af[4], bf[4];
        #pragma unroll
        for (int i = 0; i < 4; ++i)
            af[i] = *(const bf16x8*)(&As[cur][wr * 64 + i * 16 + r][rc]);
        #pragma unroll
        for (int j = 0; j < 4; ++j)
            bf[j] = *(const bf16x8*)(&Bs[cur][wc * 64 + j * 16 + r][rc]);
        __builtin_amdgcn_s_setprio(1);
        #pragma unroll
        for (int j = 0; j < 4; ++j)
            #pragma unroll
            for (int i = 0; i < 4; ++i)
                acc[j][i] = __builtin_amdgcn_mfma_f32_16x16x32_bf16(bf[j], af[i], acc[j][i], 0, 0, 0);
        __builtin_amdgcn_s_setprio(0);
        asm volatile("s_waitcnt lgkmcnt(0)" ::: "memory");     // reads of buf cur drained
        __builtin_amdgcn_sched_barrier(0);
    }
#undef STAGE

    // epilogue: row = ...+i*16+r, colbase = ...+j*16+g*4
    #pragma unroll
    for (int i = 0; i < 4; ++i) {
        const int row = bm * 128 + wr * 64 + i * 16 + r;
        size_t orow;
        if (EPI == 2) {
            int win = row >> 6, tok = row & 63;
            int bb = win >> 6, wib = win & 63;
            int h = (((wib >> 3) << 3) + (tok >> 3) + shift) & 63;
            int w = (((wib & 7) << 3) + (tok & 7) + shift) & 63;
            orow = (size_t)bb * 4096 + h * 64 + w;
        } else {
            orow = (size_t)row;
        }
        #pragma unroll
        for (int j = 0; j < 4; ++j) {
            const int colb = bn * 128 + wc * 64 + j * 16 + g * 4;
            const float4 bv = *(const float4*)(bias + colb);
            if (EPI == 0) {
                u16x4 o;
                o[0] = f2b(acc[j][i][0] + bv.x);
                o[1] = f2b(acc[j][i][1] + bv.y);
                o[2] = f2b(acc[j][i][2] + bv.z);
                o[3] = f2b(acc[j][i][3] + bv.w);
                *(u16x4*)((u16*)out + (size_t)row * N + colb) = o;
            } else if (EPI == 1) {
                u16x4 o;
                o[0] = f2b(fast_gelu(acc[j][i][0] + bv.x));
                o[1] = f2b(fast_gelu(acc[j][i][1] + bv.y));
                o[2] = f2b(fast_gelu(acc[j][i][2] + bv.z));
                o[3] = f2b(fast_gelu(acc[j][i][3] + bv.w));
                *(u16x4*)((u16*)out + (size_t)row * N + colb) = o;
            } else {
                const float4 rv = *(const float4*)(resid + orow * N + colb);
                float4 o;
                o.x = rv.x + acc[j][i][0] + bv.x;
                o.y = rv.y + acc[j][i][1] + bv.y;
                o.z = rv.z + acc[j][i][2] + bv.z;
                o.w = rv.w + acc[j][i][3] + bv.w;
                *(float4*)((float*)out + orow * N + colb) = o;
            }
        }
    }
}

// ---------------- MFMA attention: one block per window, wave = 2 heads -----
template<int SHIFTED>
__global__ __launch_bounds__(256)
void attn_mfma(const u16* __restrict__ qkv, const float* __restrict__ bmT,
               u16* __restrict__ out)
{
    __shared__ u16 pbuf[4][64 * 72];
    __shared__ u16 vbuf[4][32 * 72];
    const int tid = threadIdx.x, lane = tid & 63, wv = tid >> 6;
    const int g = lane >> 4, r = lane & 15;
    const int win = blockIdx.x;
    u16* P  = pbuf[wv];
    u16* Vt = vbuf[wv];
    const u16* base = qkv + (size_t)win * 64 * 768;
    int cls = 0;
    if (SHIFTED) {
        int wib = win & 63;
        cls = (((wib >> 3) == 7) ? 2 : 0) + (((wib & 7) == 7) ? 1 : 0);
    }
    const float sc = 0.17677669529663687f * 1.4426950408889634f;

    for (int hh = 0; hh < 2; ++hh) {
        const int h = wv * 2 + hh;
        const float* bmh = bmT + ((size_t)cls * 8 + h) * 4096;
        bf16x8 kf[4], qf[4];
        #pragma unroll
        for (int i = 0; i < 4; ++i) {
            kf[i] = *(const bf16x8*)(base + (size_t)(i * 16 + r) * 768 + 256 + h * 32 + g * 8);
            qf[i] = *(const bf16x8*)(base + (size_t)(i * 16 + r) * 768 +       h * 32 + g * 8);
        }
        #pragma unroll
        for (int d0 = 0; d0 < 32; d0 += 8) {
            u16x8 vv = *(const u16x8*)(base + (size_t)lane * 768 + 512 + h * 32 + d0);
            #pragma unroll
            for (int e = 0; e < 8; ++e) Vt[(d0 + e) * 72 + lane] = vv[e];
        }
        f32x4 acc[4][4] = {};
        #pragma unroll
        for (int i = 0; i < 4; ++i)
            #pragma unroll
            for (int j = 0; j < 4; ++j)
                acc[i][j] = __builtin_amdgcn_mfma_f32_16x16x32_bf16(kf[i], qf[j], acc[i][j], 0, 0, 0);
        #pragma unroll
        for (int i = 0; i < 4; ++i) {
            const int kb = (i * 16 + g * 4) * 64;
            #pragma unroll
            for (int j = 0; j < 4; ++j) {
                const int qq = j * 16 + r;
                #pragma unroll
                for (int rr = 0; rr < 4; ++rr)
                    acc[i][j][rr] = acc[i][j][rr] * sc + bmh[kb + rr * 64 + qq];
            }
        }
        float inv_[4];
        #pragma unroll
        for (int j = 0; j < 4; ++j) {
            float m = acc[0][j][0];
            #pragma unroll
            for (int i = 0; i < 4; ++i)
                #pragma unroll
                for (int rr = 0; rr < 4; ++rr) m = fmaxf(m, acc[i][j][rr]);
            m = fmaxf(m, __shfl_xor(m, 16));
            m = fmaxf(m, __shfl_xor(m, 32));
            float s = 0.f;
            #pragma unroll
            for (int i = 0; i < 4; ++i)
                #pragma unroll
                for (int rr = 0; rr < 4; ++rr) {
                    float p = exp2f(acc[i][j][rr] - m);
                    acc[i][j][rr] = p; s += p;
                }
            s += __shfl_xor(s, 16);
            s += __shfl_xor(s, 32);
            inv_[j] = 1.f / s;
        }
        #pragma unroll
        for (int j = 0; j < 4; ++j) {
            const float iv = inv_[j];
            #pragma unroll
            for (int i = 0; i < 4; ++i) {
                u16x4 w;
                #pragma unroll
                for (int rr = 0; rr < 4; ++rr) w[rr] = f2b(acc[i][j][rr] * iv);
                *(u16x4*)(P + (j * 16 + r) * 72 + i * 16 + g * 4) = w;
            }
        }
        f32x4 o[2][4] = {};
        #pragma unroll
        for (int ks = 0; ks < 2; ++ks) {
            bf16x8 pa[4], vb[2];
            #pragma unroll
            for (int i = 0; i < 4; ++i)
                pa[i] = *(const bf16x8*)(P + (i * 16 + r) * 72 + ks * 32 + g * 8);
            #pragma unroll
            for (int j = 0; j < 2; ++j)
                vb[j] = *(const bf16x8*)(Vt + (j * 16 + r) * 72 + ks * 32 + g * 8);
            #pragma unroll
            for (int j = 0; j < 2; ++j)
                #pragma unroll
                for (int i = 0; i < 4; ++i)
                    o[j][i] = __builtin_amdgcn_mfma_f32_16x16x32_bf16(vb[j], pa[i], o[j][i], 0, 0, 0);
        }
        u16* op = out + (size_t)win * 64 * 256 + h * 32;
        #pragma unroll
        for (int i = 0; i < 4; ++i) {
            const int qrow = i * 16 + r;
            #pragma unroll
            for (int j = 0; j < 2; ++j) {
                u16x4 w;
                #pragma unroll
                for (int rr = 0; rr < 4; ++rr) w[rr] = f2b(o[j][i][rr]);
                *(u16x4*)(op + (size_t)qrow * 256 + j * 16 + g * 4) = w;
            }
        }
    }
}

// ---------------------------------------------------------------------------
extern "C" void kernel_launch(void* const* d_in, const int* in_sizes, int n_in,
                              void* d_out, int out_size, void* d_ws, size_t ws_size,
                              hipStream_t stream)
{
    (void)in_sizes; (void)n_in; (void)out_size; (void)ws_size;
    const float* x = (const float*)d_in[0];
    char* ws = (char*)d_ws;
    size_t off = 0;
    auto alloc = [&](size_t bytes) { void* p = ws + off; off += (bytes + 255) & ~(size_t)255; return p; };

    u16 *wtq[2], *wto[2], *wt1[2], *wt2[2];
    float* bmT[2];
    for (int i = 0; i < 2; ++i) {
        wtq[i] = (u16*)alloc((size_t)768 * 256 * 2);
        wto[i] = (u16*)alloc((size_t)256 * 256 * 2);
        wt1[i] = (u16*)alloc((size_t)1024 * 256 * 2);
        wt2[i] = (u16*)alloc((size_t)256 * 1024 * 2);
        bmT[i] = (float*)alloc((size_t)4 * 8 * 64 * 64 * 4);
    }
    u16*  xw  = (u16*)alloc((size_t)65536 * 256 * 2);
    u16*  big = (u16*)alloc((size_t)65536 * 1024 * 2);
    float* x1 = (float*)alloc((size_t)65536 * 256 * 4);
    float* outp = (float*)d_out;

    for (int blk = 0; blk < 2; ++blk) {
        const float* const* P = (const float* const*)(d_in + 1 + blk * 15);
        transpose_w<<<dim3(768 / 32, 256 / 32), 256, 0, stream>>>(P[2], wtq[blk], 256, 768);
        transpose_w<<<dim3(256 / 32, 256 / 32), 256, 0, stream>>>(P[5], wto[blk], 256, 256);
        transpose_w<<<dim3(1024 / 32, 256 / 32), 256, 0, stream>>>(P[11], wt1[blk], 256, 1024);
        transpose_w<<<dim3(256 / 32, 1024 / 32), 256, 0, stream>>>(P[13], wt2[blk], 1024, 256);
        build_bias<<<512, 256, 0, stream>>>(P[4], bmT[blk]);
    }

    for (int blk = 0; blk < 2; ++blk) {
        const float* const* P = (const float* const*)(d_in + 1 + blk * 15);
        const int sh = blk ? 4 : 0;
        const float* xin = blk ? outp : x;

        ln_win_kernel<<<16384, 256, 0, stream>>>(xin, P[0], P[1], xw, sh);
        gemm_k4<0><<<dim3(6, 512), 256, 0, stream>>>(xw, wtq[blk], P[3], big, nullptr, 65536, 768, 256, 0);
        if (blk) attn_mfma<1><<<1024, 256, 0, stream>>>(big, bmT[blk], xw);
        else     attn_mfma<0><<<1024, 256, 0, stream>>>(big, bmT[blk], xw);
        gemm_k4<2><<<dim3(2, 512), 256, 0, stream>>>(xw, wto[blk], P[6], x1, xin, 65536, 256, 256, sh);
        ln2_kernel<<<16384, 256, 0, stream>>>(x1, P[7], P[8], P[9], P[10], xw);
        gemm_k4<1><<<dim3(8, 512), 256, 0, stream>>>(xw, wt1[blk], P[12], big, nullptr, 65536, 1024, 256, 0);
        gemm_k4<3><<<dim3(2, 512), 256, 0, stream>>>(big, wt2[blk], P[14], outp, x1, 65536, 256, 1024, 0);
    }
}